// Round 2
// baseline (233.395 us; speedup 1.0000x reference)
//
#include <hip/hip_runtime.h>
#include <math.h>

#define DIM 512
#define NB 256
#define KMAX 12   // Taylor terms (powers A^1..A^12)

using bf16x8 = __attribute__((ext_vector_type(8))) short;
using f32x4  = __attribute__((ext_vector_type(4))) float;
using float4v = __attribute__((ext_vector_type(4))) float;
using ushort4v = __attribute__((ext_vector_type(4))) unsigned short;

__device__ __forceinline__ unsigned short f2b(float f) {
    union { float f; unsigned int u; } v; v.f = f;
    unsigned int r = v.u + 0x7fffu + ((v.u >> 16) & 1u);
    return (unsigned short)(r >> 16);
}
__device__ __forceinline__ float b2f(unsigned short u) {
    union { unsigned int u; float f; } v; v.u = ((unsigned int)u) << 16;
    return v.f;
}
__device__ __forceinline__ ushort4v f2b4(float4v v) {
    ushort4v o;
    o.x = f2b(v.x); o.y = f2b(v.y); o.z = f2b(v.z); o.w = f2b(v.w);
    return o;
}

__device__ __forceinline__ void block_reduce2(float& s, float& q, float* sb1, float* sb2)
{
    int tid = threadIdx.x;
    #pragma unroll
    for (int off = 32; off > 0; off >>= 1) {
        s += __shfl_down(s, off);
        q += __shfl_down(q, off);
    }
    if ((tid & 63) == 0) { sb1[tid >> 6] = s; sb2[tid >> 6] = q; }
    __syncthreads();
    s = sb1[0] + sb1[1] + sb1[2] + sb1[3];
    q = sb2[0] + sb2[1] + sb2[2] + sb2[3];
    __syncthreads();
}

// ---------------------------------------------------------------------------
// Batched bf16 MFMA GEMM, BK=128.  C[m,n]=sum_k X[m,k]W[n,k]+b.
// acc: 0=store, 1=Cf+=, 2=atomicAdd(Cf), 3=fused LSTM-cell epilogue (s=tr_row0,
//      requires gate-interleaved W layout).  Ct: transposed dual-write.
// Tile decode: m-fastest + bijective XCD-chunk swizzle so all M-tiles of a
// weight panel run on one XCD (L2 reuse).  lp.lnd_y==blockIdx.y -> LN branch.
// ---------------------------------------------------------------------------
struct GemmDesc {
    const unsigned short* X;
    const unsigned short* W;
    const float* bias;
    float* Cf;
    unsigned short* Cb;
    unsigned short* Ct;
    int M, N, K, ldX, ldW, ldC, tr_row0, acc;
};
struct GemmArgs { GemmDesc d[8]; };
struct LnParams {
    const float* pre; const float* g; const float* beta;
    const float* w2; const float* b2; float* delta; float* coeff;
    int lnd_y;
    // shared LSTM aux (for acc==3 descs)
    const float* cin; const float* bih; const float* bhh; const float* decays;
    float* hout; float* cout; unsigned short* combb;
};

__global__ __launch_bounds__(256) void gemm_mfma(GemmArgs args, LnParams lp)
{
    __shared__ unsigned short lsA[2][8192];
    __shared__ unsigned short lsB[2][8192];
    __shared__ float sb1[4], sb2[4];

    if ((int)blockIdx.y == lp.lnd_y) {
        int b = blockIdx.x, tid = threadIdx.x;
        int i0 = tid, i1 = tid + 256;
        float x0 = lp.pre[(size_t)b * DIM + i0];
        float x1 = lp.pre[(size_t)b * DIM + i1];
        float s = x0 + x1, q = x0 * x0 + x1 * x1;
        block_reduce2(s, q, sb1, sb2);
        float mean = s * (1.f / DIM);
        float var  = q * (1.f / DIM) - mean * mean;
        float inv  = rsqrtf(var + 1e-5f);
        float y0 = (x0 - mean) * inv * lp.g[i0] + lp.beta[i0];
        float y1 = (x1 - mean) * inv * lp.g[i1] + lp.beta[i1];
        float h0 = 0.5f * y0 * (1.f + erff(y0 * 0.70710678118654752f));
        float h1 = 0.5f * y1 * (1.f + erff(y1 * 0.70710678118654752f));
        float p = h0 * lp.w2[i0] + h1 * lp.w2[i1];
        float dummy = 0.f;
        block_reduce2(p, dummy, sb1, sb2);
        if (tid == 0) {
            float z = p + lp.b2[0];
            float d = (z > 20.f) ? z : log1pf(expf(z));
            lp.delta[b] = d;
            float c = 1.f;
            lp.coeff[b] = 1.f;
            for (int k = 1; k <= KMAX; ++k) { c *= d / (float)k; lp.coeff[k * 256 + b] = c; }
        }
        return;
    }

    GemmDesc de = args.d[blockIdx.y];
    int tmm = de.M >> 6;
    int tiles = tmm * (de.N >> 6);
    int t = blockIdx.x;
    if (t >= tiles) return;
    // bijective XCD-chunk swizzle (round-robin -> contiguous chunk per XCD)
    int qc = tiles >> 3, rc = tiles & 7;
    int xcd = t & 7, li = t >> 3;
    int tt = (xcd < rc) ? (xcd * (qc + 1) + li) : (rc * (qc + 1) + (xcd - rc) * qc + li);
    int m0 = (tt % tmm) << 6;     // m fastest: M-tiles of one weight panel adjacent
    int n0 = (tt / tmm) << 6;

    int tid = threadIdx.x;
    int w = tid >> 6;
    int l = tid & 63;
    int nkt = de.K >> 7;      // BK=128

    int srow = w * 16 + (l >> 2);
    int schk = l & 3;
    const unsigned short* gA = de.X + (size_t)(m0 + srow) * de.ldX + schk * 8;
    const unsigned short* gB = de.W + (size_t)(n0 + srow) * de.ldW + schk * 8;
    unsigned short* lA = &lsA[0][(w * 64 + l) * 8];
    unsigned short* lB = &lsB[0][(w * 64 + l) * 8];

#define STAGE(bufi, kt)                                                          \
    do {                                                                         \
        for (int hh = 0; hh < 4; ++hh) {                                         \
            __builtin_amdgcn_global_load_lds(                                    \
                (const __attribute__((address_space(1))) unsigned int*)(gA + (size_t)(kt) * 128 + hh * 32), \
                (__attribute__((address_space(3))) unsigned int*)(lA + (bufi) * 8192 + hh * 2048), 16, 0, 0); \
            __builtin_amdgcn_global_load_lds(                                    \
                (const __attribute__((address_space(1))) unsigned int*)(gB + (size_t)(kt) * 128 + hh * 32), \
                (__attribute__((address_space(3))) unsigned int*)(lB + (bufi) * 8192 + hh * 2048), 16, 0, 0); \
        }                                                                        \
    } while (0)

    int mbase = (w >> 1) * 32;
    int nbase = (w & 1) * 32;

    f32x4 acc[2][2];
    #pragma unroll
    for (int i = 0; i < 2; ++i)
        #pragma unroll
        for (int j = 0; j < 2; ++j)
            acc[i][j] = (f32x4){0.f, 0.f, 0.f, 0.f};

    int kg = l >> 4;
    int fr = l & 15;
    int aslot = (mbase * 4 + fr * 4 + kg) * 8;
    int bslot = (nbase * 4 + fr * 4 + kg) * 8;

    STAGE(0, 0);

    for (int kt = 0; kt < nkt; ++kt) {
        __syncthreads();
        if (kt + 1 < nkt) STAGE((kt + 1) & 1, kt + 1);

        const unsigned short* bufA = &lsA[kt & 1][0];
        const unsigned short* bufB = &lsB[kt & 1][0];
        #pragma unroll
        for (int h = 0; h < 4; ++h) {
            bf16x8 a0 = *(const bf16x8*)(bufA + h * 2048 + aslot);
            bf16x8 a1 = *(const bf16x8*)(bufA + h * 2048 + aslot + 512);
            bf16x8 b0 = *(const bf16x8*)(bufB + h * 2048 + bslot);
            bf16x8 b1 = *(const bf16x8*)(bufB + h * 2048 + bslot + 512);
            acc[0][0] = __builtin_amdgcn_mfma_f32_16x16x32_bf16(a0, b0, acc[0][0], 0, 0, 0);
            acc[0][1] = __builtin_amdgcn_mfma_f32_16x16x32_bf16(a0, b1, acc[0][1], 0, 0, 0);
            acc[1][0] = __builtin_amdgcn_mfma_f32_16x16x32_bf16(a1, b0, acc[1][0], 0, 0, 0);
            acc[1][1] = __builtin_amdgcn_mfma_f32_16x16x32_bf16(a1, b1, acc[1][1], 0, 0, 0);
        }
    }

    if (de.acc == 3) {
        // ---- fused LSTM cell epilogue ----
        // tile cols (gate-interleaved W): col = gate*16 + dsub, d = n0/4 + dsub
        __syncthreads();
        float* tile = (float*)lsA;            // [64][65] f32 (16.6 KB)
        #pragma unroll
        for (int mi = 0; mi < 2; ++mi)
            #pragma unroll
            for (int ni = 0; ni < 2; ++ni) {
                int ct = nbase + ni * 16 + fr;
                #pragma unroll
                for (int r = 0; r < 4; ++r) {
                    int rt = mbase + mi * 16 + kg * 4 + r;
                    tile[rt * 65 + ct] = acc[mi][ni][r];
                }
            }
        __syncthreads();
        int s = de.tr_row0;
        int d0 = n0 >> 2;                     // (n0/64)*16
        float dec = lp.decays[s];
        for (int cell = tid; cell < 1024; cell += 256) {
            int row = cell >> 4, dsub = cell & 15;
            int d = d0 + dsub;
            int b = m0 + row;
            float vgi = tile[row * 65 +      dsub] + lp.bih[s * 2048 +        d] + lp.bhh[s * 2048 +        d];
            float vgf = tile[row * 65 + 16 + dsub] + lp.bih[s * 2048 +  512 + d] + lp.bhh[s * 2048 +  512 + d];
            float vgg = tile[row * 65 + 32 + dsub] + lp.bih[s * 2048 + 1024 + d] + lp.bhh[s * 2048 + 1024 + d];
            float vgo = tile[row * 65 + 48 + dsub] + lp.bih[s * 2048 + 1536 + d] + lp.bhh[s * 2048 + 1536 + d];
            float cc = lp.cin[(size_t)s * 131072 + (size_t)b * 512 + d];
            float ig = 1.f / (1.f + expf(-vgi));
            float fg = 1.f / (1.f + expf(-vgf));
            float g_ = tanhf(vgg);
            float og = 1.f / (1.f + expf(-vgo));
            float craw = fg * cc + ig * g_;
            float hn = og * tanhf(craw);
            lp.hout[(size_t)s * 131072 + (size_t)b * 512 + d] = hn;
            lp.cout[(size_t)s * 131072 + (size_t)b * 512 + d] = dec * cc + (1.f - dec) * craw;
            lp.combb[(size_t)b * 2048 + 512 + s * 512 + d] = f2b(hn);
        }
        return;
    }

    #pragma unroll
    for (int mi = 0; mi < 2; ++mi) {
        #pragma unroll
        for (int ni = 0; ni < 2; ++ni) {
            int col = n0 + nbase + ni * 16 + fr;
            float bv = de.bias ? de.bias[col] : 0.f;
            #pragma unroll
            for (int r = 0; r < 4; ++r) {
                int row = m0 + mbase + mi * 16 + (l >> 4) * 4 + r;
                float v = acc[mi][ni][r] + bv;
                if (de.Cf) {
                    if (de.acc == 2)      atomicAdd(&de.Cf[(size_t)row * de.ldC + col], v);
                    else if (de.acc == 1) de.Cf[(size_t)row * de.ldC + col] += v;
                    else                  de.Cf[(size_t)row * de.ldC + col] = v;
                } else {
                    de.Cb[(size_t)row * de.ldC + col] = f2b(v);
                }
                if (de.Ct && row >= de.tr_row0)
                    de.Ct[(size_t)col * 512 + (row - de.tr_row0)] = f2b(v);
            }
        }
    }
#undef STAGE
}

// ---------------------------------------------------------------------------
// Unified prep: 13 convert segments (optional gate-interleave row map) +
// two 512x512 f32->bf16 transposes + pbc = proj_b + P2 @ aout_b (f32 direct).
// Grid 2562 x 256.
// ---------------------------------------------------------------------------
#define NSEG 13
struct PrepArgs {
    const float* sA[NSEG]; const float* sB[NSEG]; unsigned short* dst[NSEG];
    int n4[NSEG], dRL4[NSEG], sRLA4[NSEG], sRLB4[NSEG], half4[NSEG], offA[NSEG], gmap[NSEG];
    const float* A; unsigned short* ATb;
    const float* W2src; unsigned short* W2dst;
    const float* projw; const float* projb; const float* aoutb; float* pbc;
};
__global__ __launch_bounds__(256) void prep_kernel(PrepArgs a)
{
    __shared__ float tile[32][33];
    int bid = blockIdx.x, tid = threadIdx.x;
    if (bid < 2048) {
        const int gstride = 2048 * 256;
        int g0 = bid * 256 + tid;
        for (int seg = 0; seg < NSEG; ++seg) {
            int n4 = a.n4[seg];
            const float* sA = a.sA[seg];
            const float* sB = a.sB[seg];
            unsigned short* d = a.dst[seg];
            int dRL4 = a.dRL4[seg], sRLA4 = a.sRLA4[seg], sRLB4 = a.sRLB4[seg];
            int half4 = a.half4[seg], offA = a.offA[seg], gm = a.gmap[seg];
            for (int i = g0; i < n4; i += gstride) {
                int r = i / dRL4, c = i - r * dRL4;
                int rs = gm ? (((r >> 4) & 3) * 512 + ((r >> 6) << 4) + (r & 15)) : r;
                const float* src = (c < half4)
                    ? sA + ((size_t)rs * sRLA4 + offA + c) * 4
                    : sB + ((size_t)rs * sRLB4 + (c - half4)) * 4;
                float4v v = *(const float4v*)src;
                *(ushort4v*)(d + (size_t)i * 4) = f2b4(v);
            }
        }
    } else if (bid < 2560) {
        int tt = bid - 2048;
        const float* src = a.A;
        unsigned short* dst = a.ATb;
        if (tt >= 256) { tt -= 256; src = a.W2src; dst = a.W2dst; }
        int bx = tt & 15, by = tt >> 4;
        int tx = tid & 31, ty = tid >> 5;
        #pragma unroll
        for (int i = 0; i < 32; i += 8)
            tile[ty + i][tx] = src[(size_t)(by * 32 + ty + i) * 512 + bx * 32 + tx];
        __syncthreads();
        #pragma unroll
        for (int i = 0; i < 32; i += 8)
            dst[(size_t)(bx * 32 + ty + i) * 512 + by * 32 + tx] = f2b(tile[tx][ty + i]);
    } else {
        // pbc[i] = proj_b[i] + sum_j proj_w[i, 512+j] * aout_b[j]  (f32 direct)
        int i = (bid - 2560) * 256 + tid;     // 0..511
        const float* pr = a.projw + (size_t)i * 2560 + 512;
        float acc = 0.f;
        for (int j = 0; j < 512; j += 4) {
            float4v w = *(const float4v*)(pr + j);
            float4v ab = *(const float4v*)(a.aoutb + j);
            acc += w.x * ab.x + w.y * ab.y + w.z * ab.z + w.w * ab.w;
        }
        a.pbc[i] = a.projb[i] + acc;
    }
}

// ---------------------------------------------------------------------------
// Pointwise: Taylor accum (K=12) only (LSTM cell fused into gates GEMM).
// combb hssm slice written here.  Grid 128 x 256.
// ---------------------------------------------------------------------------
__global__ void pointwise_fused(
    const float* __restrict__ Tm, const float* __restrict__ coeff,
    const float* __restrict__ h_prev, const float* __restrict__ delta,
    const float* __restrict__ Bx, float* __restrict__ hssm,
    unsigned short* __restrict__ combb)
{
    int idx4 = blockIdx.x * 256 + threadIdx.x;
    int base = idx4 * 4;
    int b = base >> 9, i = base & 511;
    const float* Tr = Tm + (size_t)b * (KMAX * DIM) + i;
    float4v a = *(const float4v*)(h_prev + base);
    #pragma unroll
    for (int k = 1; k <= KMAX; ++k) {
        float c = coeff[k * 256 + b];
        float4v t = *(const float4v*)(Tr + (size_t)(k - 1) * DIM);
        a.x += c * t.x; a.y += c * t.y; a.z += c * t.z; a.w += c * t.w;
    }
    float dl = delta[b];
    float4v bx = *(const float4v*)(Bx + base);
    a.x += dl * bx.x; a.y += dl * bx.y; a.z += dl * bx.z; a.w += dl * bx.w;
    *(float4v*)(hssm + base) = a;
    *(ushort4v*)(combb + (size_t)b * 2048 + i) = f2b4(a);
}

// ---------------------------------------------------------------------------
// Fused tail: attn softmax + out = LN(projA + ctx @ M2^T).
// M2 = P2 @ aout_w precomputed in batch1; aout_b@P2^T folded into projA bias.
// One block per row b.
// ---------------------------------------------------------------------------
__global__ __launch_bounds__(256) void tail_kernel(
    const unsigned short* __restrict__ qb, const unsigned short* __restrict__ kvb,
    const unsigned short* __restrict__ M2b, const float* __restrict__ projA,
    const float* __restrict__ fin_g, const float* __restrict__ fin_beta,
    float* __restrict__ outp)
{
    __shared__ float ctxs[512];
    __shared__ float sb1[4], sb2[4];
    int b = blockIdx.x, tid = threadIdx.x;

    if (tid < 128) {
        int h = tid >> 4, sub = (tid & 15) * 4;
        int col = h * 64 + sub;
        ushort4v q4 = *(const ushort4v*)(qb + (size_t)b * 512 + col);
        float qf[4] = { b2f(q4.x), b2f(q4.y), b2f(q4.z), b2f(q4.w) };
        float p[3];
        ushort4v k4[3], v4[3];
        #pragma unroll
        for (int s = 0; s < 3; ++s) {
            k4[s] = *(const ushort4v*)(kvb + (size_t)s * 262144 + (size_t)b * 1024 + col);
            v4[s] = *(const ushort4v*)(kvb + (size_t)s * 262144 + (size_t)b * 1024 + 512 + col);
            p[s] = qf[0] * b2f(k4[s].x) + qf[1] * b2f(k4[s].y)
                 + qf[2] * b2f(k4[s].z) + qf[3] * b2f(k4[s].w);
        }
        #pragma unroll
        for (int off = 1; off < 16; off <<= 1) {
            p[0] += __shfl_xor(p[0], off);
            p[1] += __shfl_xor(p[1], off);
            p[2] += __shfl_xor(p[2], off);
        }
        const float scale = 0.125f;
        float p0 = p[0] * scale, p1 = p[1] * scale, p2 = p[2] * scale;
        float m = fmaxf(p0, fmaxf(p1, p2));
        float w0 = expf(p0 - m), w1 = expf(p1 - m), w2 = expf(p2 - m);
        float invs = 1.f / (w0 + w1 + w2);
        ctxs[col + 0] = (w0 * b2f(v4[0].x) + w1 * b2f(v4[1].x) + w2 * b2f(v4[2].x)) * invs;
        ctxs[col + 1] = (w0 * b2f(v4[0].y) + w1 * b2f(v4[1].y) + w2 * b2f(v4[2].y)) * invs;
        ctxs[col + 2] = (w0 * b2f(v4[0].z) + w1 * b2f(v4[1].z) + w2 * b2f(v4[2].z)) * invs;
        ctxs[col + 3] = (w0 * b2f(v4[0].w) + w1 * b2f(v4[1].w) + w2 * b2f(v4[2].w)) * invs;
    }
    __syncthreads();

    float x0 = projA[(size_t)b * 512 + tid];
    float x1 = projA[(size_t)b * 512 + tid + 256];
    {
        const unsigned short* mr0 = M2b + (size_t)tid * 512;
        const unsigned short* mr1 = M2b + (size_t)(tid + 256) * 512;
        for (int k = 0; k < 512; k += 8) {
            ushort4v a0 = *(const ushort4v*)(mr0 + k);
            ushort4v a1 = *(const ushort4v*)(mr0 + k + 4);
            ushort4v c0 = *(const ushort4v*)(mr1 + k);
            ushort4v c1 = *(const ushort4v*)(mr1 + k + 4);
            float t0 = ctxs[k+0], t1 = ctxs[k+1], t2 = ctxs[k+2], t3 = ctxs[k+3];
            float t4 = ctxs[k+4], t5 = ctxs[k+5], t6 = ctxs[k+6], t7 = ctxs[k+7];
            x0 += t0*b2f(a0.x) + t1*b2f(a0.y) + t2*b2f(a0.z) + t3*b2f(a0.w)
                + t4*b2f(a1.x) + t5*b2f(a1.y) + t6*b2f(a1.z) + t7*b2f(a1.w);
            x1 += t0*b2f(c0.x) + t1*b2f(c0.y) + t2*b2f(c0.z) + t3*b2f(c0.w)
                + t4*b2f(c1.x) + t5*b2f(c1.y) + t6*b2f(c1.z) + t7*b2f(c1.w);
        }
    }

    float s = x0 + x1, q = x0 * x0 + x1 * x1;
    block_reduce2(s, q, sb1, sb2);
    float mean = s * (1.f / DIM);
    float var  = q * (1.f / DIM) - mean * mean;
    float inv  = rsqrtf(var + 1e-5f);
    outp[(size_t)b * DIM + tid]       = (x0 - mean) * inv * fin_g[tid]       + fin_beta[tid];
    outp[(size_t)b * DIM + tid + 256] = (x1 - mean) * inv * fin_g[tid + 256] + fin_beta[tid + 256];
}

// ---------------------------------------------------------------------------
extern "C" void kernel_launch(void* const* d_in, const int* in_sizes, int n_in,
                              void* d_out, int out_size, void* d_ws, size_t ws_size,
                              hipStream_t stream)
{
    const float* x        = (const float*)d_in[0];
    const float* h_prev   = (const float*)d_in[1];
    const float* lstm_h   = (const float*)d_in[2];
    const float* lstm_c   = (const float*)d_in[3];
    const float* A        = (const float*)d_in[4];
    const float* Bm       = (const float*)d_in[5];
    const float* dn_w1    = (const float*)d_in[6];
    const float* dn_b1    = (const float*)d_in[7];
    const float* dn_g     = (const float*)d_in[8];
    const float* dn_beta  = (const float*)d_in[9];
    const float* dn_w2    = (const float*)d_in[10];
    const float* dn_b2    = (const float*)d_in[11];
    const float* wih      = (const float*)d_in[12];
    const float* whh      = (const float*)d_in[13];
    const float* bih      = (const float*)d_in[14];
    const float* bhh      = (const float*)d_in[15];
    const float* decays   = (const float*)d_in[16];
    const float* ain_w    = (const float*)d_in[17];
    const float* ain_b    = (const float*)d_in[18];
    const float* aout_w   = (const float*)d_in[19];
    const float* aout_b   = (const float*)d_in[20];
    const float* proj_w   = (const float*)d_in[21];
    const float* proj_b   = (const float*)d_in[22];
    const float* proj_g   = (const float*)d_in[23];
    const float* proj_bt  = (const float*)d_in[24];

    float* out  = (float*)d_out;
    float* hssm = out + 131072;
    float* hnew = out + 262144;
    float* cnew = out + 655360;

    // ---- workspace (bf16 section) ----
    unsigned short* us = (unsigned short*)d_ws;
    unsigned short* hpb     = us;                  // 131072
    unsigned short* ATb     = us + 131072;         // 262144
    unsigned short* dn_w1b  = us + 393216;         // 262144
    unsigned short* Bmb     = us + 655360;         // 262144
    unsigned short* ain_wb  = us + 917504;         // 786432
    unsigned short* proj_wb = us + 1703936;        // 1048576 (512x2048 packed [P0|P1])
    unsigned short* P2b     = us + 2752512;        // 262144
    unsigned short* aout_wTb= us + 3014656;        // 262144 (aout_w^T)
    unsigned short* Pw      = us + 3276800;        // 8*262144 [A^1..A^8]
    unsigned short* Qa      = us + 5373952;        // 262144
    unsigned short* Qb      = us + 5636096;        // 262144
    unsigned short* Wcat    = us + 5898240;        // 6291456 (gate-interleaved rows)
    unsigned short* Xcat    = us + 12189696;       // 786432
    unsigned short* combb   = us + 12976128;       // 524288 (256x2048) [hssm|hnew*3]
    unsigned short* qb      = us + 13500416;       // 131072
    unsigned short* kvb     = us + 13631488;       // 786432
    unsigned short* U8b     = us + 14417920;       // 131072 (bf16 A^8 h)
    // ---- fp32 section ----
    float* fbase  = (float*)(us + 14548992);
    float* pre1   = fbase;                         // 131072 (reused as projout)
    float* delta  = fbase + 131072;                // 256
    float* coeff  = fbase + 131328;                // 13*256
    float* Bx     = fbase + 134656;                // 131072
    float* Tm     = fbase + 265728;                // 256*6144
    float* pbc    = fbase + 1838592;               // 512  (proj_b + P2@aout_b)
    unsigned short* M2b = (unsigned short*)(fbase + 1839616); // 262144 (P2@aout_w bf16)
    float* projout = pre1;

    // ---- shared LnParams base (lstm aux shared by all launches) ----
    LnParams lpOff;
    lpOff.pre = nullptr; lpOff.g = nullptr; lpOff.beta = nullptr;
    lpOff.w2 = nullptr; lpOff.b2 = nullptr; lpOff.delta = nullptr; lpOff.coeff = nullptr;
    lpOff.lnd_y = -1;
    lpOff.cin = lstm_c; lpOff.bih = bih; lpOff.bhh = bhh; lpOff.decays = decays;
    lpOff.hout = hnew; lpOff.cout = cnew; lpOff.combb = combb;

    // ---- 1. unified prep (13 segments + A^T + aout_w^T + pbc) ----
    PrepArgs pa;
    int sidx = 0;
    auto LIN = [&](const float* s, unsigned short* d, int n4) {
        pa.sA[sidx]=s; pa.sB[sidx]=s; pa.dst[sidx]=d; pa.n4[sidx]=n4;
        pa.dRL4[sidx]=n4; pa.sRLA4[sidx]=0; pa.sRLB4[sidx]=0;
        pa.half4[sidx]=n4; pa.offA[sidx]=0; pa.gmap[sidx]=0; ++sidx;
    };
    LIN(h_prev, hpb,     32768);
    LIN(A,      Pw,      65536);
    LIN(dn_w1,  dn_w1b,  65536);
    LIN(Bm,     Bmb,     65536);
    LIN(ain_w,  ain_wb,  196608);
    pa.sA[sidx]=proj_w; pa.sB[sidx]=proj_w + 1024; pa.dst[sidx]=proj_wb; pa.n4[sidx]=262144;
    pa.dRL4[sidx]=512; pa.sRLA4[sidx]=640; pa.sRLB4[sidx]=640; pa.half4[sidx]=128; pa.offA[sidx]=0; pa.gmap[sidx]=0; ++sidx;
    pa.sA[sidx]=proj_w; pa.sB[sidx]=proj_w; pa.dst[sidx]=P2b; pa.n4[sidx]=65536;
    pa.dRL4[sidx]=128; pa.sRLA4[sidx]=640; pa.sRLB4[sidx]=640; pa.half4[sidx]=128; pa.offA[sidx]=128; pa.gmap[sidx]=0; ++sidx;
    for (int s = 0; s < 3; ++s) {
        pa.sA[sidx]=wih + (size_t)s*1048576; pa.sB[sidx]=whh + (size_t)s*1048576;
        pa.dst[sidx]=Wcat + (size_t)s*2097152; pa.n4[sidx]=524288;
        pa.dRL4[sidx]=256; pa.sRLA4[sidx]=128; pa.sRLB4[sidx]=128; pa.half4[sidx]=128; pa.offA[sidx]=0;
        pa.gmap[sidx]=1; ++sidx;    // gate-interleaved rows for fused-cell epilogue
    }
    for (int s = 0; s < 3; ++s) {
        pa.sA[sidx]=x; pa.sB[sidx]=lstm_h + (size_t)s*131072;
        pa.dst[sidx]=Xcat + (size_t)s*262144; pa.n4[sidx]=65536;
        pa.dRL4[sidx]=256; pa.sRLA4[sidx]=128; pa.sRLB4[sidx]=128; pa.half4[sidx]=128; pa.offA[sidx]=0;
        pa.gmap[sidx]=0; ++sidx;
    }
    pa.A = A; pa.ATb = ATb;
    pa.W2src = aout_w; pa.W2dst = aout_wTb;
    pa.projw = proj_w; pa.projb = proj_b; pa.aoutb = aout_b; pa.pbc = pbc;
    prep_kernel<<<2562, 256, 0, stream>>>(pa);

    GemmArgs ga;
    // ---- 2. batch1: dense1, Bx, G1 (A^2 + Q2), LSTM gates x3 (fused cell),
    //                 M2 = P2 @ aout_w ----
    ga.d[0] = { Xcat, dn_w1b, dn_b1, pre1, nullptr, nullptr, 256, 512, 512, 1024, 512, 512, 0, 0 };
    ga.d[1] = { Xcat, Bmb,    nullptr, Bx,  nullptr, nullptr, 256, 512, 512, 1024, 512, 512, 0, 0 };
    ga.d[2] = { Pw, ATb, nullptr, nullptr, Pw + 1*262144, Qa, 512, 512, 512, 512, 512, 512, 0, 0 };
    for (int s = 0; s < 3; ++s)
        ga.d[3 + s] = { Xcat + (size_t)s * 262144, Wcat + (size_t)s * 2097152, nullptr,
                        nullptr, nullptr, nullptr,
                        256, 2048, 1024, 1024, 1024, 2048, s, 3 };
    ga.d[6] = { P2b, aout_wTb, nullptr, nullptr, M2b, nullptr, 512, 512, 512, 512, 512, 512, 0, 0 };
    gemm_mfma<<<dim3(128, 7), 256, 0, stream>>>(ga, lpOff);

    // ---- 3. G2 [A^3,A^4]+Q4  +  fused LN/GELU/delta (y==1) ----
    LnParams lp1 = lpOff;
    lp1.pre = pre1; lp1.g = dn_g; lp1.beta = dn_beta; lp1.w2 = dn_w2; lp1.b2 = dn_b2;
    lp1.delta = delta; lp1.coeff = coeff; lp1.lnd_y = 1;
    ga.d[0] = { Pw, Qa, nullptr, nullptr, Pw + 2*262144, Qb, 1024, 512, 512, 512, 512, 512, 512, 0 };
    gemm_mfma<<<dim3(256, 2), 256, 0, stream>>>(ga, lp1);

    // ---- 4. G3 [A^5..A^8] ----
    ga.d[0] = { Pw, Qb, nullptr, nullptr, Pw + 4*262144, nullptr, 2048, 512, 512, 512, 512, 512, 0, 0 };
    gemm_mfma<<<dim3(256, 1), 256, 0, stream>>>(ga, lpOff);

    // ---- 5. Taylor1 (k=1..8, N=4096) + U8 = bf16(A^8 h) ----
    ga.d[0] = { hpb, Pw, nullptr, Tm, nullptr, nullptr, 256, 4096, 512, 512, 512, 6144, 0, 0 };
    ga.d[1] = { hpb, Pw + 7*262144, nullptr, nullptr, U8b, nullptr, 256, 512, 512, 512, 512, 512, 0, 0 };
    gemm_mfma<<<dim3(256, 2), 256, 0, stream>>>(ga, lpOff);

    // ---- 6. Taylor2: T[k=9..12] = (A^j)(A^8 h), j=1..4 ----
    ga.d[0] = { U8b, Pw, nullptr, Tm + 4096, nullptr, nullptr, 256, 2048, 512, 512, 512, 6144, 0, 0 };
    gemm_mfma<<<dim3(128, 1), 256, 0, stream>>>(ga, lpOff);

    // ---- 7. pointwise (taylor accum + combb hssm slice) ----
    pointwise_fused<<<128, 256, 0, stream>>>(Tm, coeff, h_prev, delta, Bx, hssm, combb);

    // ---- 8. q + kv x3 + projA (K=2048, bias=pbc, store) ----
    ga.d[0] = { combb, ain_wb, ain_b, nullptr, qb, nullptr, 256, 512, 512, 2048, 512, 512, 0, 0 };
    for (int s = 0; s < 3; ++s)
        ga.d[1 + s] = { combb + 512 + (size_t)s * 512, ain_wb + 262144, ain_b + 512,
                        nullptr, kvb + (size_t)s * 262144, nullptr, 256, 1024, 512, 2048, 512, 1024, 0, 0 };
    ga.d[4] = { combb, proj_wb, pbc, projout, nullptr, nullptr, 256, 512, 2048, 2048, 2048, 512, 0, 0 };
    gemm_mfma<<<dim3(64, 5), 256, 0, stream>>>(ga, lpOff);

    // ---- 9. fused tail: attn + single matvec (ctx @ M2^T) + final LN ----
    tail_kernel<<<256, 256, 0, stream>>>(qb, kvb, M2b, projout,
                                         proj_g, proj_bt, out);
}

// Round 3
// 222.890 us; speedup vs baseline: 1.0471x; 1.0471x over previous
//
#include <hip/hip_runtime.h>
#include <math.h>

#define DIM 512
#define NB 256
#define KMAX 12   // Taylor terms (powers A^1..A^12)

using bf16x8 = __attribute__((ext_vector_type(8))) short;
using f32x4  = __attribute__((ext_vector_type(4))) float;
using float4v = __attribute__((ext_vector_type(4))) float;
using ushort4v = __attribute__((ext_vector_type(4))) unsigned short;

__device__ __forceinline__ unsigned short f2b(float f) {
    union { float f; unsigned int u; } v; v.f = f;
    unsigned int r = v.u + 0x7fffu + ((v.u >> 16) & 1u);
    return (unsigned short)(r >> 16);
}
__device__ __forceinline__ float b2f(unsigned short u) {
    union { unsigned int u; float f; } v; v.u = ((unsigned int)u) << 16;
    return v.f;
}
__device__ __forceinline__ ushort4v f2b4(float4v v) {
    ushort4v o;
    o.x = f2b(v.x); o.y = f2b(v.y); o.z = f2b(v.z); o.w = f2b(v.w);
    return o;
}

__device__ __forceinline__ void block_reduce2(float& s, float& q, float* sb1, float* sb2)
{
    int tid = threadIdx.x;
    #pragma unroll
    for (int off = 32; off > 0; off >>= 1) {
        s += __shfl_down(s, off);
        q += __shfl_down(q, off);
    }
    if ((tid & 63) == 0) { sb1[tid >> 6] = s; sb2[tid >> 6] = q; }
    __syncthreads();
    s = sb1[0] + sb1[1] + sb1[2] + sb1[3];
    q = sb2[0] + sb2[1] + sb2[2] + sb2[3];
    __syncthreads();
}

// ---------------------------------------------------------------------------
// Batched bf16 MFMA GEMM, BK=128.  C[m,n]=sum_k X[m,k]W[n,k]+b.
// acc: 0=store, 1=Cf+=, 2=atomicAdd(Cf), 3=fused LSTM-cell epilogue.
// Cf (f32, ldC) and Cb (bf16, ldCb) may BOTH be set (dual write).
// Ct: transposed bf16 dual-write.  Tile decode: m-fastest + bijective
// XCD-chunk swizzle.  lp.lnd_y==blockIdx.y -> fused LN/GELU/delta branch.
// ---------------------------------------------------------------------------
struct GemmDesc {
    const unsigned short* X;
    const unsigned short* W;
    const float* bias;
    float* Cf;
    unsigned short* Cb;
    unsigned short* Ct;
    int M, N, K, ldX, ldW, ldC, ldCb, tr_row0, acc;
};
struct GemmArgs { GemmDesc d[8]; };
struct LnParams {
    const float* pre; const float* g; const float* beta;
    const float* w2; const float* b2; float* delta; float* coeff;
    int lnd_y;
    // shared LSTM aux (for acc==3 descs)
    const float* cin; const float* bih; const float* bhh; const float* decays;
    float* hout; float* cout; unsigned short* combb;
};

__global__ __launch_bounds__(256) void gemm_mfma(GemmArgs args, LnParams lp)
{
    __shared__ unsigned short lsA[2][8192];
    __shared__ unsigned short lsB[2][8192];
    __shared__ float sb1[4], sb2[4];

    if ((int)blockIdx.y == lp.lnd_y) {
        int b = blockIdx.x, tid = threadIdx.x;
        int i0 = tid, i1 = tid + 256;
        float x0 = lp.pre[(size_t)b * DIM + i0];
        float x1 = lp.pre[(size_t)b * DIM + i1];
        float s = x0 + x1, q = x0 * x0 + x1 * x1;
        block_reduce2(s, q, sb1, sb2);
        float mean = s * (1.f / DIM);
        float var  = q * (1.f / DIM) - mean * mean;
        float inv  = rsqrtf(var + 1e-5f);
        float y0 = (x0 - mean) * inv * lp.g[i0] + lp.beta[i0];
        float y1 = (x1 - mean) * inv * lp.g[i1] + lp.beta[i1];
        float h0 = 0.5f * y0 * (1.f + erff(y0 * 0.70710678118654752f));
        float h1 = 0.5f * y1 * (1.f + erff(y1 * 0.70710678118654752f));
        float p = h0 * lp.w2[i0] + h1 * lp.w2[i1];
        float dummy = 0.f;
        block_reduce2(p, dummy, sb1, sb2);
        if (tid == 0) {
            float z = p + lp.b2[0];
            float d = (z > 20.f) ? z : log1pf(expf(z));
            lp.delta[b] = d;
            float c = 1.f;
            lp.coeff[b] = 1.f;
            for (int k = 1; k <= KMAX; ++k) { c *= d / (float)k; lp.coeff[k * 256 + b] = c; }
        }
        return;
    }

    GemmDesc de = args.d[blockIdx.y];
    int tmm = de.M >> 6;
    int tiles = tmm * (de.N >> 6);
    int t = blockIdx.x;
    if (t >= tiles) return;
    // bijective XCD-chunk swizzle (round-robin -> contiguous chunk per XCD)
    int qc = tiles >> 3, rc = tiles & 7;
    int xcd = t & 7, li = t >> 3;
    int tt = (xcd < rc) ? (xcd * (qc + 1) + li) : (rc * (qc + 1) + (xcd - rc) * qc + li);
    int m0 = (tt % tmm) << 6;     // m fastest: M-tiles of one weight panel adjacent
    int n0 = (tt / tmm) << 6;

    int tid = threadIdx.x;
    int w = tid >> 6;
    int l = tid & 63;
    int nkt = de.K >> 7;      // BK=128

    int srow = w * 16 + (l >> 2);
    int schk = l & 3;
    const unsigned short* gA = de.X + (size_t)(m0 + srow) * de.ldX + schk * 8;
    const unsigned short* gB = de.W + (size_t)(n0 + srow) * de.ldW + schk * 8;
    unsigned short* lA = &lsA[0][(w * 64 + l) * 8];
    unsigned short* lB = &lsB[0][(w * 64 + l) * 8];

#define STAGE(bufi, kt)                                                          \
    do {                                                                         \
        for (int hh = 0; hh < 4; ++hh) {                                         \
            __builtin_amdgcn_global_load_lds(                                    \
                (const __attribute__((address_space(1))) unsigned int*)(gA + (size_t)(kt) * 128 + hh * 32), \
                (__attribute__((address_space(3))) unsigned int*)(lA + (bufi) * 8192 + hh * 2048), 16, 0, 0); \
            __builtin_amdgcn_global_load_lds(                                    \
                (const __attribute__((address_space(1))) unsigned int*)(gB + (size_t)(kt) * 128 + hh * 32), \
                (__attribute__((address_space(3))) unsigned int*)(lB + (bufi) * 8192 + hh * 2048), 16, 0, 0); \
        }                                                                        \
    } while (0)

    int mbase = (w >> 1) * 32;
    int nbase = (w & 1) * 32;

    f32x4 acc[2][2];
    #pragma unroll
    for (int i = 0; i < 2; ++i)
        #pragma unroll
        for (int j = 0; j < 2; ++j)
            acc[i][j] = (f32x4){0.f, 0.f, 0.f, 0.f};

    int kg = l >> 4;
    int fr = l & 15;
    int aslot = (mbase * 4 + fr * 4 + kg) * 8;
    int bslot = (nbase * 4 + fr * 4 + kg) * 8;

    STAGE(0, 0);

    for (int kt = 0; kt < nkt; ++kt) {
        __syncthreads();
        if (kt + 1 < nkt) STAGE((kt + 1) & 1, kt + 1);

        const unsigned short* bufA = &lsA[kt & 1][0];
        const unsigned short* bufB = &lsB[kt & 1][0];
        #pragma unroll
        for (int h = 0; h < 4; ++h) {
            bf16x8 a0 = *(const bf16x8*)(bufA + h * 2048 + aslot);
            bf16x8 a1 = *(const bf16x8*)(bufA + h * 2048 + aslot + 512);
            bf16x8 b0 = *(const bf16x8*)(bufB + h * 2048 + bslot);
            bf16x8 b1 = *(const bf16x8*)(bufB + h * 2048 + bslot + 512);
            acc[0][0] = __builtin_amdgcn_mfma_f32_16x16x32_bf16(a0, b0, acc[0][0], 0, 0, 0);
            acc[0][1] = __builtin_amdgcn_mfma_f32_16x16x32_bf16(a0, b1, acc[0][1], 0, 0, 0);
            acc[1][0] = __builtin_amdgcn_mfma_f32_16x16x32_bf16(a1, b0, acc[1][0], 0, 0, 0);
            acc[1][1] = __builtin_amdgcn_mfma_f32_16x16x32_bf16(a1, b1, acc[1][1], 0, 0, 0);
        }
    }

    if (de.acc == 3) {
        // ---- fused LSTM cell epilogue ----
        __syncthreads();
        float* tile = (float*)lsA;            // [64][65] f32 (16.6 KB)
        #pragma unroll
        for (int mi = 0; mi < 2; ++mi)
            #pragma unroll
            for (int ni = 0; ni < 2; ++ni) {
                int ct = nbase + ni * 16 + fr;
                #pragma unroll
                for (int r = 0; r < 4; ++r) {
                    int rt = mbase + mi * 16 + kg * 4 + r;
                    tile[rt * 65 + ct] = acc[mi][ni][r];
                }
            }
        __syncthreads();
        int s = de.tr_row0;
        int d0 = n0 >> 2;                     // (n0/64)*16
        float dec = lp.decays[s];
        for (int cell = tid; cell < 1024; cell += 256) {
            int row = cell >> 4, dsub = cell & 15;
            int d = d0 + dsub;
            int b = m0 + row;
            float vgi = tile[row * 65 +      dsub] + lp.bih[s * 2048 +        d] + lp.bhh[s * 2048 +        d];
            float vgf = tile[row * 65 + 16 + dsub] + lp.bih[s * 2048 +  512 + d] + lp.bhh[s * 2048 +  512 + d];
            float vgg = tile[row * 65 + 32 + dsub] + lp.bih[s * 2048 + 1024 + d] + lp.bhh[s * 2048 + 1024 + d];
            float vgo = tile[row * 65 + 48 + dsub] + lp.bih[s * 2048 + 1536 + d] + lp.bhh[s * 2048 + 1536 + d];
            float cc = lp.cin[(size_t)s * 131072 + (size_t)b * 512 + d];
            float ig = 1.f / (1.f + expf(-vgi));
            float fg = 1.f / (1.f + expf(-vgf));
            float g_ = tanhf(vgg);
            float og = 1.f / (1.f + expf(-vgo));
            float craw = fg * cc + ig * g_;
            float hn = og * tanhf(craw);
            lp.hout[(size_t)s * 131072 + (size_t)b * 512 + d] = hn;
            lp.cout[(size_t)s * 131072 + (size_t)b * 512 + d] = dec * cc + (1.f - dec) * craw;
            lp.combb[(size_t)b * 2048 + 512 + s * 512 + d] = f2b(hn);
        }
        return;
    }

    #pragma unroll
    for (int mi = 0; mi < 2; ++mi) {
        #pragma unroll
        for (int ni = 0; ni < 2; ++ni) {
            int col = n0 + nbase + ni * 16 + fr;
            float bv = de.bias ? de.bias[col] : 0.f;
            #pragma unroll
            for (int r = 0; r < 4; ++r) {
                int row = m0 + mbase + mi * 16 + (l >> 4) * 4 + r;
                float v = acc[mi][ni][r] + bv;
                if (de.Cf) {
                    if (de.acc == 2)      atomicAdd(&de.Cf[(size_t)row * de.ldC + col], v);
                    else if (de.acc == 1) de.Cf[(size_t)row * de.ldC + col] += v;
                    else                  de.Cf[(size_t)row * de.ldC + col] = v;
                }
                if (de.Cb)
                    de.Cb[(size_t)row * de.ldCb + col] = f2b(v);
                if (de.Ct && row >= de.tr_row0)
                    de.Ct[(size_t)col * 512 + (row - de.tr_row0)] = f2b(v);
            }
        }
    }
#undef STAGE
}

// ---------------------------------------------------------------------------
// Unified prep: 13 convert segments (optional gate-interleave row map) +
// two 512x512 f32->bf16 transposes + pbc = proj_b + P2 @ aout_b (f32 direct).
// Grid 2562 x 256.
// ---------------------------------------------------------------------------
#define NSEG 13
struct PrepArgs {
    const float* sA[NSEG]; const float* sB[NSEG]; unsigned short* dst[NSEG];
    int n4[NSEG], dRL4[NSEG], sRLA4[NSEG], sRLB4[NSEG], half4[NSEG], offA[NSEG], gmap[NSEG];
    const float* A; unsigned short* ATb;
    const float* W2src; unsigned short* W2dst;
    const float* projw; const float* projb; const float* aoutb; float* pbc;
};
__global__ __launch_bounds__(256) void prep_kernel(PrepArgs a)
{
    __shared__ float tile[32][33];
    int bid = blockIdx.x, tid = threadIdx.x;
    if (bid < 2048) {
        const int gstride = 2048 * 256;
        int g0 = bid * 256 + tid;
        for (int seg = 0; seg < NSEG; ++seg) {
            int n4 = a.n4[seg];
            const float* sA = a.sA[seg];
            const float* sB = a.sB[seg];
            unsigned short* d = a.dst[seg];
            int dRL4 = a.dRL4[seg], sRLA4 = a.sRLA4[seg], sRLB4 = a.sRLB4[seg];
            int half4 = a.half4[seg], offA = a.offA[seg], gm = a.gmap[seg];
            for (int i = g0; i < n4; i += gstride) {
                int r = i / dRL4, c = i - r * dRL4;
                int rs = gm ? (((r >> 4) & 3) * 512 + ((r >> 6) << 4) + (r & 15)) : r;
                const float* src = (c < half4)
                    ? sA + ((size_t)rs * sRLA4 + offA + c) * 4
                    : sB + ((size_t)rs * sRLB4 + (c - half4)) * 4;
                float4v v = *(const float4v*)src;
                *(ushort4v*)(d + (size_t)i * 4) = f2b4(v);
            }
        }
    } else if (bid < 2560) {
        int tt = bid - 2048;
        const float* src = a.A;
        unsigned short* dst = a.ATb;
        if (tt >= 256) { tt -= 256; src = a.W2src; dst = a.W2dst; }
        int bx = tt & 15, by = tt >> 4;
        int tx = tid & 31, ty = tid >> 5;
        #pragma unroll
        for (int i = 0; i < 32; i += 8)
            tile[ty + i][tx] = src[(size_t)(by * 32 + ty + i) * 512 + bx * 32 + tx];
        __syncthreads();
        #pragma unroll
        for (int i = 0; i < 32; i += 8)
            dst[(size_t)(bx * 32 + ty + i) * 512 + by * 32 + tx] = f2b(tile[tx][ty + i]);
    } else {
        // pbc[i] = proj_b[i] + sum_j proj_w[i, 512+j] * aout_b[j]  (f32 direct)
        int i = (bid - 2560) * 256 + tid;     // 0..511
        const float* pr = a.projw + (size_t)i * 2560 + 512;
        float acc = 0.f;
        for (int j = 0; j < 512; j += 4) {
            float4v w = *(const float4v*)(pr + j);
            float4v ab = *(const float4v*)(a.aoutb + j);
            acc += w.x * ab.x + w.y * ab.y + w.z * ab.z + w.w * ab.w;
        }
        a.pbc[i] = a.projb[i] + acc;
    }
}

// ---------------------------------------------------------------------------
// Pointwise: Taylor accum (K=12) only (LSTM cell fused into gates GEMM).
// combb hssm slice written here.  Grid 128 x 256.
// ---------------------------------------------------------------------------
__global__ void pointwise_fused(
    const float* __restrict__ Tm, const float* __restrict__ coeff,
    const float* __restrict__ h_prev, const float* __restrict__ delta,
    const float* __restrict__ Bx, float* __restrict__ hssm,
    unsigned short* __restrict__ combb)
{
    int idx4 = blockIdx.x * 256 + threadIdx.x;
    int base = idx4 * 4;
    int b = base >> 9, i = base & 511;
    const float* Tr = Tm + (size_t)b * (KMAX * DIM) + i;
    float4v a = *(const float4v*)(h_prev + base);
    #pragma unroll
    for (int k = 1; k <= KMAX; ++k) {
        float c = coeff[k * 256 + b];
        float4v t = *(const float4v*)(Tr + (size_t)(k - 1) * DIM);
        a.x += c * t.x; a.y += c * t.y; a.z += c * t.z; a.w += c * t.w;
    }
    float dl = delta[b];
    float4v bx = *(const float4v*)(Bx + base);
    a.x += dl * bx.x; a.y += dl * bx.y; a.z += dl * bx.z; a.w += dl * bx.w;
    *(float4v*)(hssm + base) = a;
    *(ushort4v*)(combb + (size_t)b * 2048 + i) = f2b4(a);
}

// ---------------------------------------------------------------------------
// Fused tail: attn softmax + out = LN(projA + ctx @ M2^T).
// M2 = P2 @ aout_w precomputed in batch1; aout_b@P2^T folded into projA bias.
// One block per row b.
// ---------------------------------------------------------------------------
__global__ __launch_bounds__(256) void tail_kernel(
    const unsigned short* __restrict__ qb, const unsigned short* __restrict__ kvb,
    const unsigned short* __restrict__ M2b, const float* __restrict__ projA,
    const float* __restrict__ fin_g, const float* __restrict__ fin_beta,
    float* __restrict__ outp)
{
    __shared__ float ctxs[512];
    __shared__ float sb1[4], sb2[4];
    int b = blockIdx.x, tid = threadIdx.x;

    if (tid < 128) {
        int h = tid >> 4, sub = (tid & 15) * 4;
        int col = h * 64 + sub;
        ushort4v q4 = *(const ushort4v*)(qb + (size_t)b * 512 + col);
        float qf[4] = { b2f(q4.x), b2f(q4.y), b2f(q4.z), b2f(q4.w) };
        float p[3];
        ushort4v k4[3], v4[3];
        #pragma unroll
        for (int s = 0; s < 3; ++s) {
            k4[s] = *(const ushort4v*)(kvb + (size_t)s * 262144 + (size_t)b * 1024 + col);
            v4[s] = *(const ushort4v*)(kvb + (size_t)s * 262144 + (size_t)b * 1024 + 512 + col);
            p[s] = qf[0] * b2f(k4[s].x) + qf[1] * b2f(k4[s].y)
                 + qf[2] * b2f(k4[s].z) + qf[3] * b2f(k4[s].w);
        }
        #pragma unroll
        for (int off = 1; off < 16; off <<= 1) {
            p[0] += __shfl_xor(p[0], off);
            p[1] += __shfl_xor(p[1], off);
            p[2] += __shfl_xor(p[2], off);
        }
        const float scale = 0.125f;
        float p0 = p[0] * scale, p1 = p[1] * scale, p2 = p[2] * scale;
        float m = fmaxf(p0, fmaxf(p1, p2));
        float w0 = expf(p0 - m), w1 = expf(p1 - m), w2 = expf(p2 - m);
        float invs = 1.f / (w0 + w1 + w2);
        ctxs[col + 0] = (w0 * b2f(v4[0].x) + w1 * b2f(v4[1].x) + w2 * b2f(v4[2].x)) * invs;
        ctxs[col + 1] = (w0 * b2f(v4[0].y) + w1 * b2f(v4[1].y) + w2 * b2f(v4[2].y)) * invs;
        ctxs[col + 2] = (w0 * b2f(v4[0].z) + w1 * b2f(v4[1].z) + w2 * b2f(v4[2].z)) * invs;
        ctxs[col + 3] = (w0 * b2f(v4[0].w) + w1 * b2f(v4[1].w) + w2 * b2f(v4[2].w)) * invs;
    }
    __syncthreads();

    float x0 = projA[(size_t)b * 512 + tid];
    float x1 = projA[(size_t)b * 512 + tid + 256];
    {
        const unsigned short* mr0 = M2b + (size_t)tid * 512;
        const unsigned short* mr1 = M2b + (size_t)(tid + 256) * 512;
        for (int k = 0; k < 512; k += 8) {
            ushort4v a0 = *(const ushort4v*)(mr0 + k);
            ushort4v a1 = *(const ushort4v*)(mr0 + k + 4);
            ushort4v c0 = *(const ushort4v*)(mr1 + k);
            ushort4v c1 = *(const ushort4v*)(mr1 + k + 4);
            float t0 = ctxs[k+0], t1 = ctxs[k+1], t2 = ctxs[k+2], t3 = ctxs[k+3];
            float t4 = ctxs[k+4], t5 = ctxs[k+5], t6 = ctxs[k+6], t7 = ctxs[k+7];
            x0 += t0*b2f(a0.x) + t1*b2f(a0.y) + t2*b2f(a0.z) + t3*b2f(a0.w)
                + t4*b2f(a1.x) + t5*b2f(a1.y) + t6*b2f(a1.z) + t7*b2f(a1.w);
            x1 += t0*b2f(c0.x) + t1*b2f(c0.y) + t2*b2f(c0.z) + t3*b2f(c0.w)
                + t4*b2f(c1.x) + t5*b2f(c1.y) + t6*b2f(c1.z) + t7*b2f(c1.w);
        }
    }

    float s = x0 + x1, q = x0 * x0 + x1 * x1;
    block_reduce2(s, q, sb1, sb2);
    float mean = s * (1.f / DIM);
    float var  = q * (1.f / DIM) - mean * mean;
    float inv  = rsqrtf(var + 1e-5f);
    outp[(size_t)b * DIM + tid]       = (x0 - mean) * inv * fin_g[tid]       + fin_beta[tid];
    outp[(size_t)b * DIM + tid + 256] = (x1 - mean) * inv * fin_g[tid + 256] + fin_beta[tid + 256];
}

// ---------------------------------------------------------------------------
extern "C" void kernel_launch(void* const* d_in, const int* in_sizes, int n_in,
                              void* d_out, int out_size, void* d_ws, size_t ws_size,
                              hipStream_t stream)
{
    const float* x        = (const float*)d_in[0];
    const float* h_prev   = (const float*)d_in[1];
    const float* lstm_h   = (const float*)d_in[2];
    const float* lstm_c   = (const float*)d_in[3];
    const float* A        = (const float*)d_in[4];
    const float* Bm       = (const float*)d_in[5];
    const float* dn_w1    = (const float*)d_in[6];
    const float* dn_b1    = (const float*)d_in[7];
    const float* dn_g     = (const float*)d_in[8];
    const float* dn_beta  = (const float*)d_in[9];
    const float* dn_w2    = (const float*)d_in[10];
    const float* dn_b2    = (const float*)d_in[11];
    const float* wih      = (const float*)d_in[12];
    const float* whh      = (const float*)d_in[13];
    const float* bih      = (const float*)d_in[14];
    const float* bhh      = (const float*)d_in[15];
    const float* decays   = (const float*)d_in[16];
    const float* ain_w    = (const float*)d_in[17];
    const float* ain_b    = (const float*)d_in[18];
    const float* aout_w   = (const float*)d_in[19];
    const float* aout_b   = (const float*)d_in[20];
    const float* proj_w   = (const float*)d_in[21];
    const float* proj_b   = (const float*)d_in[22];
    const float* proj_g   = (const float*)d_in[23];
    const float* proj_bt  = (const float*)d_in[24];

    float* out  = (float*)d_out;
    float* hssm = out + 131072;
    float* hnew = out + 262144;
    float* cnew = out + 655360;

    // ---- workspace (bf16 section) ----
    unsigned short* us = (unsigned short*)d_ws;
    unsigned short* hpb     = us;                  // 131072
    unsigned short* ATb     = us + 131072;         // 262144
    unsigned short* dn_w1b  = us + 393216;         // 262144
    unsigned short* Bmb     = us + 655360;         // 262144
    unsigned short* ain_wb  = us + 917504;         // 786432
    unsigned short* proj_wb = us + 1703936;        // 1048576 (512x2048 packed [P0|P1])
    unsigned short* P2b     = us + 2752512;        // 262144
    unsigned short* aout_wTb= us + 3014656;        // 262144 (aout_w^T)
    unsigned short* Pw      = us + 3276800;        // 8*262144, slots used: A,A2,A4(idx3),A8(idx7)
    unsigned short* Qa      = us + 5373952;        // 262144 (A^2 transposed)
    unsigned short* Qb      = us + 5636096;        // 262144 (A^4 transposed)
    unsigned short* Wcat    = us + 5898240;        // 6291456 (gate-interleaved rows)
    unsigned short* Xcat    = us + 12189696;       // 786432
    unsigned short* combb   = us + 12976128;       // 524288 (256x2048) [hssm|hnew*3]
    unsigned short* qb      = us + 13500416;       // 131072
    unsigned short* kvb     = us + 13631488;       // 786432
    unsigned short* Tmb     = us + 14417920;       // 524288 (256x2048 bf16: Tm1..Tm4)
    // ---- fp32 section ----
    float* fbase  = (float*)(us + 14942208);
    float* pre1   = fbase;                         // 131072 (reused as projout)
    float* delta  = fbase + 131072;                // 256
    float* coeff  = fbase + 131328;                // 13*256
    float* Bx     = fbase + 134656;                // 131072
    float* Tm     = fbase + 265728;                // 256*6144 f32
    float* pbc    = fbase + 1838592;               // 512  (proj_b + P2@aout_b)
    unsigned short* M2b = (unsigned short*)(fbase + 1839104); // 262144 (P2@aout_w bf16)
    float* projout = pre1;

    // ---- shared LnParams base (lstm aux shared by all launches) ----
    LnParams lpOff;
    lpOff.pre = nullptr; lpOff.g = nullptr; lpOff.beta = nullptr;
    lpOff.w2 = nullptr; lpOff.b2 = nullptr; lpOff.delta = nullptr; lpOff.coeff = nullptr;
    lpOff.lnd_y = -1;
    lpOff.cin = lstm_c; lpOff.bih = bih; lpOff.bhh = bhh; lpOff.decays = decays;
    lpOff.hout = hnew; lpOff.cout = cnew; lpOff.combb = combb;

    // ---- 1. unified prep (13 segments + A^T + aout_w^T + pbc) ----
    PrepArgs pa;
    int sidx = 0;
    auto LIN = [&](const float* s, unsigned short* d, int n4) {
        pa.sA[sidx]=s; pa.sB[sidx]=s; pa.dst[sidx]=d; pa.n4[sidx]=n4;
        pa.dRL4[sidx]=n4; pa.sRLA4[sidx]=0; pa.sRLB4[sidx]=0;
        pa.half4[sidx]=n4; pa.offA[sidx]=0; pa.gmap[sidx]=0; ++sidx;
    };
    LIN(h_prev, hpb,     32768);
    LIN(A,      Pw,      65536);
    LIN(dn_w1,  dn_w1b,  65536);
    LIN(Bm,     Bmb,     65536);
    LIN(ain_w,  ain_wb,  196608);
    pa.sA[sidx]=proj_w; pa.sB[sidx]=proj_w + 1024; pa.dst[sidx]=proj_wb; pa.n4[sidx]=262144;
    pa.dRL4[sidx]=512; pa.sRLA4[sidx]=640; pa.sRLB4[sidx]=640; pa.half4[sidx]=128; pa.offA[sidx]=0; pa.gmap[sidx]=0; ++sidx;
    pa.sA[sidx]=proj_w; pa.sB[sidx]=proj_w; pa.dst[sidx]=P2b; pa.n4[sidx]=65536;
    pa.dRL4[sidx]=128; pa.sRLA4[sidx]=640; pa.sRLB4[sidx]=640; pa.half4[sidx]=128; pa.offA[sidx]=128; pa.gmap[sidx]=0; ++sidx;
    for (int s = 0; s < 3; ++s) {
        pa.sA[sidx]=wih + (size_t)s*1048576; pa.sB[sidx]=whh + (size_t)s*1048576;
        pa.dst[sidx]=Wcat + (size_t)s*2097152; pa.n4[sidx]=524288;
        pa.dRL4[sidx]=256; pa.sRLA4[sidx]=128; pa.sRLB4[sidx]=128; pa.half4[sidx]=128; pa.offA[sidx]=0;
        pa.gmap[sidx]=1; ++sidx;    // gate-interleaved rows for fused-cell epilogue
    }
    for (int s = 0; s < 3; ++s) {
        pa.sA[sidx]=x; pa.sB[sidx]=lstm_h + (size_t)s*131072;
        pa.dst[sidx]=Xcat + (size_t)s*262144; pa.n4[sidx]=65536;
        pa.dRL4[sidx]=256; pa.sRLA4[sidx]=128; pa.sRLB4[sidx]=128; pa.half4[sidx]=128; pa.offA[sidx]=0;
        pa.gmap[sidx]=0; ++sidx;
    }
    pa.A = A; pa.ATb = ATb;
    pa.W2src = aout_w; pa.W2dst = aout_wTb;
    pa.projw = proj_w; pa.projb = proj_b; pa.aoutb = aout_b; pa.pbc = pbc;
    prep_kernel<<<2562, 256, 0, stream>>>(pa);

    GemmArgs ga;
    // ---- 2. L1/batch1: dense1, Bx, A^2(+A^2T), gates x3 (fused cell),
    //                    M2 = P2@aout_w, Tm1 = h@A^T-form (dual f32+bf16) ----
    ga.d[0] = { Xcat, dn_w1b, dn_b1, pre1, nullptr, nullptr, 256, 512, 512, 1024, 512, 512, 0, 0, 0 };
    ga.d[1] = { Xcat, Bmb,    nullptr, Bx,  nullptr, nullptr, 256, 512, 512, 1024, 512, 512, 0, 0, 0 };
    ga.d[2] = { Pw, ATb, nullptr, nullptr, Pw + 1*262144, Qa, 512, 512, 512, 512, 512, 512, 512, 0, 0 };
    for (int s = 0; s < 3; ++s)
        ga.d[3 + s] = { Xcat + (size_t)s * 262144, Wcat + (size_t)s * 2097152, nullptr,
                        nullptr, nullptr, nullptr,
                        256, 2048, 1024, 1024, 1024, 2048, 0, s, 3 };
    ga.d[6] = { P2b, aout_wTb, nullptr, nullptr, M2b, nullptr, 512, 512, 512, 512, 512, 512, 512, 0, 0 };
    ga.d[7] = { hpb, Pw, nullptr, Tm, Tmb, nullptr, 256, 512, 512, 512, 512, 6144, 2048, 0, 0 };
    gemm_mfma<<<dim3(128, 8), 256, 0, stream>>>(ga, lpOff);

    // ---- 3. L2: A^4(+A^4T), Tm2 = h@A^2, Tm3 = Tm1@A^2  +  LN/GELU/delta (y==3) ----
    LnParams lp1 = lpOff;
    lp1.pre = pre1; lp1.g = dn_g; lp1.beta = dn_beta; lp1.w2 = dn_w2; lp1.b2 = dn_b2;
    lp1.delta = delta; lp1.coeff = coeff; lp1.lnd_y = 3;
    ga.d[0] = { Pw + 1*262144, Qa, nullptr, nullptr, Pw + 3*262144, Qb, 512, 512, 512, 512, 512, 512, 512, 0, 0 };
    ga.d[1] = { hpb, Pw + 1*262144, nullptr, Tm + 512,  Tmb + 512,  nullptr, 256, 512, 512, 512,  512, 6144, 2048, 0, 0 };
    ga.d[2] = { Tmb, Pw + 1*262144, nullptr, Tm + 1024, Tmb + 1024, nullptr, 256, 512, 512, 2048, 512, 6144, 2048, 0, 0 };
    gemm_mfma<<<dim3(256, 4), 256, 0, stream>>>(ga, lp1);

    // ---- 4. L3: A^8 = A^4@A^4, Tm4 = h@A^4, Tm5..7 = Tm1..3@A^4 ----
    ga.d[0] = { Pw + 3*262144, Qb, nullptr, nullptr, Pw + 7*262144, nullptr, 512, 512, 512, 512, 512, 512, 512, 0, 0 };
    ga.d[1] = { hpb,        Pw + 3*262144, nullptr, Tm + 1536, Tmb + 1536, nullptr, 256, 512, 512, 512,  512, 6144, 2048, 0, 0 };
    ga.d[2] = { Tmb,        Pw + 3*262144, nullptr, Tm + 2048, nullptr, nullptr, 256, 512, 512, 2048, 512, 6144, 0, 0, 0 };
    ga.d[3] = { Tmb + 512,  Pw + 3*262144, nullptr, Tm + 2560, nullptr, nullptr, 256, 512, 512, 2048, 512, 6144, 0, 0, 0 };
    ga.d[4] = { Tmb + 1024, Pw + 3*262144, nullptr, Tm + 3072, nullptr, nullptr, 256, 512, 512, 2048, 512, 6144, 0, 0, 0 };
    gemm_mfma<<<dim3(64, 5), 256, 0, stream>>>(ga, lpOff);

    // ---- 5. L4: Tm8 = Tm4@A^4, Tm9..12 = Tm1..4@A^8 ----
    ga.d[0] = { Tmb + 1536, Pw + 3*262144, nullptr, Tm + 3584, nullptr, nullptr, 256, 512, 512, 2048, 512, 6144, 0, 0, 0 };
    ga.d[1] = { Tmb,        Pw + 7*262144, nullptr, Tm + 4096, nullptr, nullptr, 256, 512, 512, 2048, 512, 6144, 0, 0, 0 };
    ga.d[2] = { Tmb + 512,  Pw + 7*262144, nullptr, Tm + 4608, nullptr, nullptr, 256, 512, 512, 2048, 512, 6144, 0, 0, 0 };
    ga.d[3] = { Tmb + 1024, Pw + 7*262144, nullptr, Tm + 5120, nullptr, nullptr, 256, 512, 512, 2048, 512, 6144, 0, 0, 0 };
    ga.d[4] = { Tmb + 1536, Pw + 7*262144, nullptr, Tm + 5632, nullptr, nullptr, 256, 512, 512, 2048, 512, 6144, 0, 0, 0 };
    gemm_mfma<<<dim3(32, 5), 256, 0, stream>>>(ga, lpOff);

    // ---- 6. pointwise (taylor accum + combb hssm slice) ----
    pointwise_fused<<<128, 256, 0, stream>>>(Tm, coeff, h_prev, delta, Bx, hssm, combb);

    // ---- 7. q + kv x3 + projA (K=2048, bias=pbc, store) ----
    ga.d[0] = { combb, ain_wb, ain_b, nullptr, qb, nullptr, 256, 512, 512, 2048, 512, 512, 512, 0, 0 };
    for (int s = 0; s < 3; ++s)
        ga.d[1 + s] = { combb + 512 + (size_t)s * 512, ain_wb + 262144, ain_b + 512,
                        nullptr, kvb + (size_t)s * 262144, nullptr, 256, 1024, 512, 2048, 512, 1024, 1024, 0, 0 };
    ga.d[4] = { combb, proj_wb, pbc, projout, nullptr, nullptr, 256, 512, 2048, 2048, 2048, 512, 0, 0, 0 };
    gemm_mfma<<<dim3(64, 5), 256, 0, stream>>>(ga, lpOff);

    // ---- 8. fused tail: attn + single matvec (ctx @ M2^T) + final LN ----
    tail_kernel<<<256, 256, 0, stream>>>(qb, kvb, M2b, projout,
                                         proj_g, proj_bt, out);
}